// Round 2
// baseline (109.805 us; speedup 1.0000x reference)
//
#include <hip/hip_runtime.h>
#include <math.h>

#define D    32
#define PREV 64
#define HID  128
#define HDIM 64
#define NW   2112    // (D+1)*PREV
#define BPB  32      // batches per block in main kernel

// ws layout (floats):
//   [0,4096)     M[h*32+d]      = sum_p w1[d,p]*bw[h,p]
//   [4096,8192)  w2T[h*32+d]    = w2[d,h]
//   [8192,8320)  sbias[h]       = b1.bw[h,:] + bb[h]
//   [8320,8448)  c[h]           = sum_d M[h,d]*w2[d,h]
//   [8448,8480)  b2[d]

__global__ __launch_bounds__(256) void prep_kernel(
    const float* __restrict__ t,
    const float* __restrict__ hw1,
    const float* __restrict__ hb1,
    const float* __restrict__ hw2,
    const float* __restrict__ hb2,
    const float* __restrict__ bw,
    const float* __restrict__ bb,
    const float* __restrict__ w2,
    const float* __restrict__ b2,
    float* __restrict__ ws)
{
    __shared__ float hcode[HDIM];
    __shared__ float w1s[D * PREV];   // [d*64+p]
    __shared__ float b1s[PREV];
    __shared__ float MsT[D * HID];    // [d*128+h]

    const int tid = threadIdx.x;
    const float tv = t[0];

    if (tid < HDIM) {
        hcode[tid] = tanhf(tv * hw1[tid] + hb1[tid]);
    }
    __syncthreads();

    // weights[i] = hcode . hw2[i,:] + hb2[i]
    for (int i = tid; i < NW; i += 256) {
        const float4* row = reinterpret_cast<const float4*>(hw2 + i * HDIM);
        float acc = hb2[i];
        #pragma unroll
        for (int q = 0; q < 16; ++q) {
            float4 u = row[q];
            int j = q * 4;
            acc += u.x * hcode[j] + u.y * hcode[j + 1]
                 + u.z * hcode[j + 2] + u.w * hcode[j + 3];
        }
        if (i < D * PREV) w1s[i] = acc; else b1s[i - D * PREV] = acc;
    }
    __syncthreads();

    // M[h,d] = sum_p w1[d,p]*bw[h,p]
    for (int idx = tid; idx < HID * D; idx += 256) {
        int h = idx & 127, d = idx >> 7;
        const float4* bwr = reinterpret_cast<const float4*>(bw + h * PREV);
        const float* w1r = w1s + d * PREV;
        float acc = 0.f;
        #pragma unroll
        for (int q = 0; q < 16; ++q) {
            float4 u = bwr[q];
            int p = q * 4;
            acc += u.x * w1r[p] + u.y * w1r[p + 1]
                 + u.z * w1r[p + 2] + u.w * w1r[p + 3];
        }
        MsT[d * HID + h] = acc;
        ws[h * D + d] = acc;                      // M
        ws[4096 + h * D + d] = w2[d * HID + h];   // w2T
    }

    // sbias[h] = b1 . bw[h,:] + bb[h]
    if (tid < HID) {
        const float4* bwr = reinterpret_cast<const float4*>(bw + tid * PREV);
        float acc = bb[tid];
        #pragma unroll
        for (int q = 0; q < 16; ++q) {
            float4 u = bwr[q];
            int p = q * 4;
            acc += u.x * b1s[p] + u.y * b1s[p + 1]
                 + u.z * b1s[p + 2] + u.w * b1s[p + 3];
        }
        ws[8192 + tid] = acc;
    }
    if (tid < D) ws[8448 + tid] = b2[tid];
    __syncthreads();

    // c[h] = sum_d M[h,d]*w2[d,h]
    if (tid < HID) {
        float acc = 0.f;
        #pragma unroll
        for (int d = 0; d < D; ++d)
            acc += MsT[d * HID + tid] * w2[d * HID + tid];
        ws[8320 + tid] = acc;
    }
}

__global__ __launch_bounds__(256) void main_kernel(
    const float* __restrict__ y,
    const float* __restrict__ ws,
    float* __restrict__ out)
{
    __shared__ float Ms[HID][36];   // pad 36: conflict-free float4 reads across h
    __shared__ float Ws[HID][36];
    __shared__ float xs[BPB][36];
    __shared__ float sbias[HID];
    __shared__ float cs[HID];
    __shared__ float b2s[D];

    const int tid = threadIdx.x;
    const int blk = blockIdx.x;

    for (int idx = tid; idx < HID * D; idx += 256) {
        int h = idx >> 5, d = idx & 31;
        Ms[h][d] = ws[idx];
        Ws[h][d] = ws[4096 + idx];
    }
    if (tid < HID) { sbias[tid] = ws[8192 + tid]; cs[tid] = ws[8320 + tid]; }
    if (tid < D)   b2s[tid] = ws[8448 + tid];
    for (int idx = tid; idx < BPB * D; idx += 256) {
        int r = idx >> 5, c = idx & 31;
        xs[r][c] = y[(blk * BPB + r) * (D + 1) + c];
    }
    __syncthreads();

    const int bsub = tid >> 3;   // 0..31: batch within block
    const int hg   = tid & 7;    // 0..7: h-group (owns 16 of 128 h)

    float xr[D];
    const float4* xrow = reinterpret_cast<const float4*>(&xs[bsub][0]);
    #pragma unroll
    for (int q = 0; q < 8; ++q) {
        float4 v = xrow[q];
        xr[4*q] = v.x; xr[4*q+1] = v.y; xr[4*q+2] = v.z; xr[4*q+3] = v.w;
    }

    float dxp[D];
    #pragma unroll
    for (int d = 0; d < D; ++d) dxp[d] = 0.f;
    float divp = 0.f;

    #pragma unroll
    for (int k = 0; k < 16; ++k) {
        const int h = (k << 3) | hg;
        float s = sbias[h];
        const float4* mrow = reinterpret_cast<const float4*>(&Ms[h][0]);
        #pragma unroll
        for (int q = 0; q < 8; ++q) {
            float4 m = mrow[q];
            s += xr[4*q]*m.x + xr[4*q+1]*m.y + xr[4*q+2]*m.z + xr[4*q+3]*m.w;
        }
        // tanh(s) = 1 - 2/(e^{2s}+1); exact at both saturations
        float e = __expf(2.f * s);
        float a = 1.f - 2.f / (e + 1.f);
        float g = 1.f - a * a;
        divp += g * cs[h];
        const float4* wrow = reinterpret_cast<const float4*>(&Ws[h][0]);
        #pragma unroll
        for (int q = 0; q < 8; ++q) {
            float4 w = wrow[q];
            dxp[4*q]   += a * w.x;
            dxp[4*q+1] += a * w.y;
            dxp[4*q+2] += a * w.z;
            dxp[4*q+3] += a * w.w;
        }
    }

    // butterfly reduce over the 8 h-group lanes of this batch
    #pragma unroll
    for (int m = 1; m < 8; m <<= 1) {
        #pragma unroll
        for (int d = 0; d < D; ++d) dxp[d] += __shfl_xor(dxp[d], m, 64);
        divp += __shfl_xor(divp, m, 64);
    }

    if (hg == 0) {
        const int b = blk * BPB + bsub;
        float* orow = out + b * (D + 1);
        #pragma unroll
        for (int d = 0; d < D; ++d) orow[d] = dxp[d] + b2s[d];
        orow[D] = -divp;
    }
}

extern "C" void kernel_launch(void* const* d_in, const int* in_sizes, int n_in,
                              void* d_out, int out_size, void* d_ws, size_t ws_size,
                              hipStream_t stream) {
    const float* y   = (const float*)d_in[0];
    const float* t   = (const float*)d_in[1];
    const float* hw1 = (const float*)d_in[2];
    const float* hb1 = (const float*)d_in[3];
    const float* hw2 = (const float*)d_in[4];
    const float* hb2 = (const float*)d_in[5];
    const float* bw  = (const float*)d_in[6];
    const float* bb  = (const float*)d_in[7];
    const float* w2  = (const float*)d_in[8];
    const float* b2  = (const float*)d_in[9];
    float* ws  = (float*)d_ws;
    float* out = (float*)d_out;

    hipLaunchKernelGGL(prep_kernel, dim3(1), dim3(256), 0, stream,
                       t, hw1, hb1, hw2, hb2, bw, bb, w2, b2, ws);
    hipLaunchKernelGGL(main_kernel, dim3(8192 / BPB), dim3(256), 0, stream,
                       y, ws, out);
}

// Round 3
// 105.456 us; speedup vs baseline: 1.0412x; 1.0412x over previous
//
#include <hip/hip_runtime.h>
#include <math.h>

#define D    32
#define PREV 64
#define HID  128
#define HDIM 64
#define NW   2112    // (D+1)*PREV
#define BPB  32      // batches per block in main kernel

// ws layout (floats):
//   [4096,8192)   M[h*32+d]   = sum_p w1[d,p]*bw[h,p]
//   [8192,12288)  w2T[h*32+d] = w2[d,h]
//   [12288,12416) sbias[h]    = b1.bw[h,:] + bb[h]
//   [12416,12544) c[h]        = sum_d M[h,d]*w2[d,h]
//   [12544,12576) b2[d]

// grid 16 x 256: each block redundantly computes hcode + full w1/b1
// (540 KB hw2 stream shared via L2/L3 across blocks), then its own
// 8-h slice of M / sbias / c / w2T.
__global__ __launch_bounds__(256) void prep_kernel(
    const float* __restrict__ t,
    const float* __restrict__ hw1,
    const float* __restrict__ hb1,
    const float* __restrict__ hw2,
    const float* __restrict__ hb2,
    const float* __restrict__ bw,
    const float* __restrict__ bb,
    const float* __restrict__ w2,
    const float* __restrict__ b2,
    float* __restrict__ ws)
{
    __shared__ float hcode[HDIM];
    __shared__ float w1s[D][68];   // 68: rows 16B-aligned, disjoint 4-bank spans
    __shared__ float b1s[PREV];
    __shared__ float Mt[8][33];

    const int tid = threadIdx.x;
    const int blk = blockIdx.x;          // 0..15, owns h in [blk*8, blk*8+8)
    const float tv = t[0];

    if (tid < HDIM) hcode[tid] = tanhf(tv * hw1[tid] + hb1[tid]);
    __syncthreads();

    // full weights: w1[d,p], b1[p]
    for (int i = tid; i < NW; i += 256) {
        const float4* row = reinterpret_cast<const float4*>(hw2 + i * HDIM);
        float acc = hb2[i];
        #pragma unroll
        for (int q = 0; q < 16; ++q) {
            float4 u = row[q];
            int j = q * 4;
            acc += u.x * hcode[j] + u.y * hcode[j + 1]
                 + u.z * hcode[j + 2] + u.w * hcode[j + 3];
        }
        if (i < D * PREV) w1s[i >> 6][i & 63] = acc;
        else              b1s[i - D * PREV] = acc;
    }
    __syncthreads();

    // M[h,d] for this block's 8 h; one element per thread
    const int hsub = tid >> 5, d = tid & 31;
    const int h = blk * 8 + hsub;
    {
        const float4* bwr = reinterpret_cast<const float4*>(bw + h * PREV);
        float acc = 0.f;
        #pragma unroll
        for (int q = 0; q < 16; ++q) {
            float4 u = bwr[q];
            int p = q * 4;
            acc += u.x * w1s[d][p]     + u.y * w1s[d][p + 1]
                 + u.z * w1s[d][p + 2] + u.w * w1s[d][p + 3];
        }
        Mt[hsub][d] = acc;
        ws[4096 + h * D + d] = acc;              // M
        ws[8192 + h * D + d] = w2[d * HID + h];  // w2T
    }
    if (blk == 0 && tid < D) ws[12544 + tid] = b2[tid];
    __syncthreads();

    if (tid < 8) {
        const int hh = blk * 8 + tid;
        float cacc = 0.f;
        #pragma unroll
        for (int dd = 0; dd < D; ++dd)
            cacc += Mt[tid][dd] * w2[dd * HID + hh];
        float sacc = bb[hh];
        #pragma unroll
        for (int p = 0; p < PREV; ++p)
            sacc += b1s[p] * bw[hh * PREV + p];
        ws[12416 + hh] = cacc;   // c
        ws[12288 + hh] = sacc;   // sbias
    }
}

__global__ __launch_bounds__(256) void main_kernel(
    const float* __restrict__ y,
    const float* __restrict__ ws,
    float* __restrict__ out)
{
    __shared__ float Ms[HID][36];   // 8 distinct rows/wave -> disjoint bank spans
    __shared__ float Ws[HID][36];
    __shared__ float xs[BPB][36];
    __shared__ float os[BPB][33];   // staged output rows for coalesced store
    __shared__ float sbias[HID];
    __shared__ float cs[HID];
    __shared__ float b2s[D];

    const int tid = threadIdx.x;
    const int blk = blockIdx.x;

    for (int idx = tid; idx < HID * D; idx += 256) {
        int h = idx >> 5, d = idx & 31;
        Ms[h][d] = ws[4096 + idx];
        Ws[h][d] = ws[8192 + idx];
    }
    if (tid < HID) { sbias[tid] = ws[12288 + tid]; cs[tid] = ws[12416 + tid]; }
    if (tid < D)   b2s[tid] = ws[12544 + tid];
    for (int idx = tid; idx < BPB * D; idx += 256) {
        int r = idx >> 5, c = idx & 31;
        xs[r][c] = y[(blk * BPB + r) * (D + 1) + c];
    }
    __syncthreads();

    const int bsub = tid >> 3;   // 0..31: batch within block
    const int hg   = tid & 7;    // 0..7: h-group (owns 16 of 128 h)

    float xr[D];
    const float4* xrow = reinterpret_cast<const float4*>(&xs[bsub][0]);
    #pragma unroll
    for (int q = 0; q < 8; ++q) {
        float4 v = xrow[q];
        xr[4*q] = v.x; xr[4*q+1] = v.y; xr[4*q+2] = v.z; xr[4*q+3] = v.w;
    }

    float dxp[D];
    #pragma unroll
    for (int d = 0; d < D; ++d) dxp[d] = 0.f;
    float divp = 0.f;

    #pragma unroll
    for (int k = 0; k < 16; ++k) {
        const int h = (k << 3) | hg;
        float s = sbias[h];
        const float4* mrow = reinterpret_cast<const float4*>(&Ms[h][0]);
        #pragma unroll
        for (int q = 0; q < 8; ++q) {
            float4 m = mrow[q];
            s += xr[4*q]*m.x + xr[4*q+1]*m.y + xr[4*q+2]*m.z + xr[4*q+3]*m.w;
        }
        // tanh(s) = 1 - 2/(e^{2s}+1); exact at both saturations
        float e = __expf(2.f * s);
        float a = 1.f - 2.f / (e + 1.f);
        float g = 1.f - a * a;
        divp += g * cs[h];
        const float4* wrow = reinterpret_cast<const float4*>(&Ws[h][0]);
        #pragma unroll
        for (int q = 0; q < 8; ++q) {
            float4 w = wrow[q];
            dxp[4*q]   += a * w.x;
            dxp[4*q+1] += a * w.y;
            dxp[4*q+2] += a * w.z;
            dxp[4*q+3] += a * w.w;
        }
    }

    // butterfly reduce over the 8 h-group lanes of this batch
    #pragma unroll
    for (int m = 1; m < 8; m <<= 1) {
        #pragma unroll
        for (int d = 0; d < D; ++d) dxp[d] += __shfl_xor(dxp[d], m, 64);
        divp += __shfl_xor(divp, m, 64);
    }

    if (hg == 0) {
        #pragma unroll
        for (int d = 0; d < D; ++d) os[bsub][d] = dxp[d] + b2s[d];
        os[bsub][D] = -divp;
    }
    __syncthreads();

    // coalesced store of the block's 32 contiguous output rows (1056 floats)
    const float* osf = &os[0][0];
    float* obase = out + blk * (BPB * (D + 1));
    for (int idx = tid; idx < BPB * (D + 1); idx += 256)
        obase[idx] = osf[idx];
}

extern "C" void kernel_launch(void* const* d_in, const int* in_sizes, int n_in,
                              void* d_out, int out_size, void* d_ws, size_t ws_size,
                              hipStream_t stream) {
    const float* y   = (const float*)d_in[0];
    const float* t   = (const float*)d_in[1];
    const float* hw1 = (const float*)d_in[2];
    const float* hb1 = (const float*)d_in[3];
    const float* hw2 = (const float*)d_in[4];
    const float* hb2 = (const float*)d_in[5];
    const float* bw  = (const float*)d_in[6];
    const float* bb  = (const float*)d_in[7];
    const float* w2  = (const float*)d_in[8];
    const float* b2  = (const float*)d_in[9];
    float* ws  = (float*)d_ws;
    float* out = (float*)d_out;

    hipLaunchKernelGGL(prep_kernel, dim3(16), dim3(256), 0, stream,
                       t, hw1, hb1, hw2, hb2, bw, bb, w2, b2, ws);
    hipLaunchKernelGGL(main_kernel, dim3(8192 / BPB), dim3(256), 0, stream,
                       y, ws, out);
}